// Round 1
// baseline (174.526 us; speedup 1.0000x reference)
//
#include <hip/hip_runtime.h>

#define H 1024
#define W 1024
#define L 8
#define QH 1025
#define QW 1025
#define OUT0 192
#define QUANT_ELEMS (L * QH * QW)

// ws layout (u32/f32 slots): [0]=min_enc, [1]=max_enc, [2..65]=sta accumulators (f32)

__device__ __forceinline__ unsigned enc_ord(float f) {
    unsigned b = __float_as_uint(f);
    return (b & 0x80000000u) ? ~b : (b ^ 0x80000000u);
}
__device__ __forceinline__ float dec_ord(unsigned u) {
    unsigned b = (u & 0x80000000u) ? (u ^ 0x80000000u) : ~u;
    return __uint_as_float(b);
}

__global__ void k_init(unsigned* ws) {
    int t = threadIdx.x;
    if (t == 0) ws[0] = 0xFFFFFFFFu;          // min slot: encoded +inf-ish (max uint)
    else if (t == 1) ws[1] = 0u;              // max slot
    else if (t < 66) ((float*)ws)[t] = 0.0f;  // sta accumulators
}

__global__ __launch_bounds__(256) void k_minmax(const float* __restrict__ x, unsigned* ws) {
    int idx = blockIdx.x * 256 + threadIdx.x;      // 262144 threads, float4 each
    float4 v = ((const float4*)x)[idx];
    float mn = fminf(fminf(v.x, v.y), fminf(v.z, v.w));
    float mx = fmaxf(fmaxf(v.x, v.y), fmaxf(v.z, v.w));
    #pragma unroll
    for (int m = 1; m < 64; m <<= 1) {
        mn = fminf(mn, __shfl_xor(mn, m, 64));
        mx = fmaxf(mx, __shfl_xor(mx, m, 64));
    }
    if ((threadIdx.x & 63) == 0) {
        atomicMin(&ws[0], enc_ord(mn));
        atomicMax(&ws[1], enc_ord(mx));
    }
}

__global__ __launch_bounds__(256) void k_main(const float* __restrict__ x,
                                              float* __restrict__ out,
                                              const unsigned* __restrict__ ws_mm,
                                              float* __restrict__ ws_sta) {
    const float mnv = dec_ord(ws_mm[0]);
    const float mxv = dec_ord(ws_mm[1]);
    const float step = (mxv - mnv) * (1.0f / 7.0f);
    float q[L];
    #pragma unroll
    for (int i = 0; i < L; ++i) q[i] = mnv + step * (float)i;
    q[L - 1] = mxv;  // linspace endpoint exact

    float* __restrict__ quant = out + OUT0;
    float* __restrict__ co    = out + OUT0 + QUANT_ELEMS;

    const int t  = threadIdx.x;
    const int h  = blockIdx.x;       // one row per block
    const int w0 = t * 4;

    // left pixels (h, w0..w0+3)
    float4 xl = *(const float4*)(x + h * W + w0);
    float xls[4] = {xl.x, xl.y, xl.z, xl.w};
    float lv[4][L];
    #pragma unroll
    for (int p = 0; p < 4; ++p) {
        #pragma unroll
        for (int i = 0; i < L; ++i) {
            float d = xls[p] - q[i];
            lv[p][i] = __expf(-16.0f * d * d);
        }
    }

    // right (shifted) pixels quant_pad[h+1][w0+1+p]; zero at pad
    const bool hok = (h + 1 < H);
    float rv[4][L];
    #pragma unroll
    for (int p = 0; p < 4; ++p) {
        int rw = w0 + 1 + p;
        bool ok = hok && (rw < W);
        float xr = ok ? x[(h + 1) * W + rw] : 0.0f;
        #pragma unroll
        for (int j = 0; j < L; ++j) {
            float d = xr - q[j];
            rv[p][j] = ok ? __expf(-16.0f * d * d) : 0.0f;
        }
    }

    // quant writes (row stride 1025 -> scalar stores, still lane-contiguous)
    #pragma unroll
    for (int i = 0; i < L; ++i) {
        float* qp = quant + (i * QH + h) * QW + w0;
        qp[0] = lv[0][i]; qp[1] = lv[1][i]; qp[2] = lv[2][i]; qp[3] = lv[3][i];
    }

    // co-occurrence writes (float4, coalesced per plane) + sta accumulation
    float acc[64];
    #pragma unroll
    for (int i = 0; i < L; ++i) {
        #pragma unroll
        for (int j = 0; j < L; ++j) {
            float4 v;
            v.x = lv[0][i] * rv[0][j];
            v.y = lv[1][i] * rv[1][j];
            v.z = lv[2][i] * rv[2][j];
            v.w = lv[3][i] * rv[3][j];
            *(float4*)(co + ((i * L + j) * H + h) * W + w0) = v;
            acc[i * L + j] = (v.x + v.y) + (v.z + v.w);
        }
    }

    // wave butterfly allreduce of the 64 accumulators
    #pragma unroll
    for (int m = 1; m < 64; m <<= 1) {
        #pragma unroll
        for (int k = 0; k < 64; ++k) acc[k] += __shfl_xor(acc[k], m, 64);
    }

    __shared__ float lds[4][64];
    int wv = t >> 6, ln = t & 63;
    lds[wv][ln] = acc[ln];
    __syncthreads();
    if (t < 64) {
        float s = (lds[0][t] + lds[1][t]) + (lds[2][t] + lds[3][t]);
        atomicAdd(&ws_sta[t], s);
    }
}

__global__ void k_pad(float* __restrict__ out) {
    int idx = blockIdx.x * 256 + threadIdx.x;
    if (idx >= L * (QW + H)) return;  // 8 * 2049
    int i = idx / (QW + H), r = idx % (QW + H);
    float* quant = out + OUT0;
    if (r < QW) quant[(i * QH + H) * QW + r] = 0.0f;        // bottom pad row
    else        quant[(i * QH + (r - QW)) * QW + W] = 0.0f; // right pad col
}

__global__ void k_final(float* __restrict__ out,
                        const unsigned* __restrict__ ws_mm,
                        const float* __restrict__ ws_sta) {
    int t = threadIdx.x;  // 64 threads
    const float mnv = dec_ord(ws_mm[0]);
    const float mxv = dec_ord(ws_mm[1]);
    const float step = (mxv - mnv) * (1.0f / 7.0f);
    float q[L];
    #pragma unroll
    for (int i = 0; i < L; ++i) q[i] = mnv + step * (float)i;
    q[L - 1] = mxv;

    float s = ws_sta[t];
    float tot = s;
    #pragma unroll
    for (int m = 1; m < 64; m <<= 1) tot += __shfl_xor(tot, m, 64);

    out[t]       = q[t & 7];   // q_h[i][j] = q_levels[j]
    out[64 + t]  = q[t >> 3];  // q_w[i][j] = q_levels[i]
    out[128 + t] = s / tot;    // normalized sta
}

extern "C" void kernel_launch(void* const* d_in, const int* in_sizes, int n_in,
                              void* d_out, int out_size, void* d_ws, size_t ws_size,
                              hipStream_t stream) {
    const float* x = (const float*)d_in[0];
    float* out = (float*)d_out;
    unsigned* ws = (unsigned*)d_ws;
    float* ws_sta = (float*)d_ws + 2;

    k_init<<<dim3(1), dim3(66), 0, stream>>>(ws);
    k_minmax<<<dim3((H * W) / (256 * 4)), dim3(256), 0, stream>>>(x, ws);
    k_main<<<dim3(H), dim3(256), 0, stream>>>(x, out, ws, ws_sta);
    k_pad<<<dim3((L * (QW + H) + 255) / 256), dim3(256), 0, stream>>>(out);
    k_final<<<dim3(1), dim3(64), 0, stream>>>(out, ws, ws_sta);
}

// Round 2
// 75.531 us; speedup vs baseline: 2.3107x; 2.3107x over previous
//
#include <hip/hip_runtime.h>

#define H 1024
#define W 1024
#define L 8
#define QH 1025
#define QW 1025
#define OUT0 192
#define QUANT_ELEMS (L * QH * QW)

// ws (u32/f32 slots), strided to avoid same-cacheline atomic serialization:
// [0]=min_enc, [16]=max_enc, [32 + k*16]=sta[k] (k=0..63)
#define WS_MIN 0
#define WS_MAX 16
#define WS_STA 32
#define WS_STRIDE 16
#define WS_SLOTS (WS_STA + 64 * WS_STRIDE)

__device__ __forceinline__ unsigned enc_ord(float f) {
    unsigned b = __float_as_uint(f);
    return (b & 0x80000000u) ? ~b : (b ^ 0x80000000u);
}
__device__ __forceinline__ float dec_ord(unsigned u) {
    unsigned b = (u & 0x80000000u) ? (u ^ 0x80000000u) : ~u;
    return __uint_as_float(b);
}

__global__ void k_init(unsigned* ws) {
    int t = threadIdx.x;
    for (int i = t; i < WS_SLOTS; i += 256)
        ws[i] = (i == WS_MIN) ? 0xFFFFFFFFu : 0u;  // float 0.0 == 0u bits
}

__global__ __launch_bounds__(256) void k_minmax(const float4* __restrict__ x4, unsigned* ws) {
    int t = threadIdx.x;
    int gid = blockIdx.x * 256 + t;
    float mn = 1e30f, mx = -1e30f;
    #pragma unroll
    for (int i = 0; i < 4; ++i) {
        float4 v = x4[gid + i * 65536];
        mn = fminf(mn, fminf(fminf(v.x, v.y), fminf(v.z, v.w)));
        mx = fmaxf(mx, fmaxf(fmaxf(v.x, v.y), fmaxf(v.z, v.w)));
    }
    #pragma unroll
    for (int m = 1; m < 64; m <<= 1) {
        mn = fminf(mn, __shfl_xor(mn, m, 64));
        mx = fmaxf(mx, __shfl_xor(mx, m, 64));
    }
    __shared__ float smn[4], smx[4];
    if ((t & 63) == 0) { smn[t >> 6] = mn; smx[t >> 6] = mx; }
    __syncthreads();
    if (t == 0) {
        mn = fminf(fminf(smn[0], smn[1]), fminf(smn[2], smn[3]));
        mx = fmaxf(fmaxf(smx[0], smx[1]), fmaxf(smx[2], smx[3]));
        atomicMin(&ws[WS_MIN], enc_ord(mn));
        atomicMax(&ws[WS_MAX], enc_ord(mx));
    }
}

__global__ __launch_bounds__(256) void k_main(const float* __restrict__ x,
                                              float* __restrict__ out,
                                              unsigned* __restrict__ ws) {
    const float mnv = dec_ord(ws[WS_MIN]);
    const float mxv = dec_ord(ws[WS_MAX]);
    const float step = (mxv - mnv) * (1.0f / 7.0f);
    float q[L];
    #pragma unroll
    for (int i = 0; i < L; ++i) q[i] = mnv + step * (float)i;
    q[L - 1] = mxv;

    float* __restrict__ quant = out + OUT0;
    float* __restrict__ co    = out + OUT0 + QUANT_ELEMS;

    const int t = threadIdx.x, h = blockIdx.x;
    const int w0 = t * 4, lane = t & 63, wv = t >> 6;

    // left pixels (h, w0..w0+3)
    float4 xl = *(const float4*)(x + h * W + w0);
    float xls[4] = {xl.x, xl.y, xl.z, xl.w};

    // right (shifted) pixels quant_pad[h+1][w0+1+p]; zero at pad
    const bool hok = (h + 1 < H);
    float rv[4][L];
    #pragma unroll
    for (int p = 0; p < 4; ++p) {
        int rw = w0 + 1 + p;
        bool ok = hok && (rw < W);
        float xr = ok ? x[(h + 1) * W + rw] : 0.0f;
        #pragma unroll
        for (int j = 0; j < L; ++j) {
            float d = xr - q[j];
            rv[p][j] = ok ? __expf(-16.0f * d * d) : 0.0f;
        }
    }

    float acc[64];
    #pragma unroll
    for (int i = 0; i < L; ++i) {
        // compute lv for this level only (keeps live regs low)
        float lv[4];
        #pragma unroll
        for (int p = 0; p < 4; ++p) {
            float d = xls[p] - q[i];
            lv[p] = __expf(-16.0f * d * d);
        }
        float* qp = quant + (i * QH + h) * QW + w0;
        qp[0] = lv[0]; qp[1] = lv[1]; qp[2] = lv[2]; qp[3] = lv[3];

        #pragma unroll
        for (int j = 0; j < L; ++j) {
            float4 v;
            v.x = lv[0] * rv[0][j];
            v.y = lv[1] * rv[1][j];
            v.z = lv[2] * rv[2][j];
            v.w = lv[3] * rv[3][j];
            *(float4*)(co + ((i * L + j) * H + h) * W + w0) = v;
            acc[i * L + j] = (v.x + v.y) + (v.z + v.w);
        }
    }

    // pad writes (folded former k_pad): right column for this row; bottom row for planes h<8
    if (t < L) quant[(t * QH + h) * QW + W] = 0.0f;
    if (h < L) {
        for (int w = t; w < QW; w += 256) quant[(h * QH + H) * QW + w] = 0.0f;
    }

    // log2 cross-lane reduce: 63 shuffles total; lane l ends holding colsum[bitrev6(l)]
    int cnt = 64;
    #pragma unroll
    for (int s = 0; s < 6; ++s) {
        const int m = 1 << s;
        const int half = cnt >> 1;
        const bool upper = (lane & m) != 0;
        #pragma unroll
        for (int k = 0; k < half; ++k) {
            float a = acc[k], b = acc[k + half];
            float keep = upper ? b : a;
            float send = upper ? a : b;
            float recv = __shfl_xor(send, m, 64);
            acc[k] = keep + recv;
        }
        cnt = half;
    }
    const int col = __brev(lane) >> 26;  // bitrev6

    __shared__ float red[4][64];
    red[wv][col] = acc[0];
    __syncthreads();
    if (t < 64) {
        float s4 = (red[0][t] + red[1][t]) + (red[2][t] + red[3][t]);
        // one wave-op, 64 lanes -> 64 DISTINCT cachelines (stride 64B): parallel across L2 banks
        atomicAdd((float*)ws + WS_STA + t * WS_STRIDE, s4);
    }
}

__global__ void k_final(float* __restrict__ out, const unsigned* __restrict__ ws) {
    int t = threadIdx.x;  // 64 threads
    const float mnv = dec_ord(ws[WS_MIN]);
    const float mxv = dec_ord(ws[WS_MAX]);
    const float step = (mxv - mnv) * (1.0f / 7.0f);
    float q[L];
    #pragma unroll
    for (int i = 0; i < L; ++i) q[i] = mnv + step * (float)i;
    q[L - 1] = mxv;

    float s = ((const float*)ws)[WS_STA + t * WS_STRIDE];
    float tot = s;
    #pragma unroll
    for (int m = 1; m < 64; m <<= 1) tot += __shfl_xor(tot, m, 64);

    out[t]       = q[t & 7];   // q_h[i][j] = q_levels[j]
    out[64 + t]  = q[t >> 3];  // q_w[i][j] = q_levels[i]
    out[128 + t] = s / tot;    // normalized sta
}

extern "C" void kernel_launch(void* const* d_in, const int* in_sizes, int n_in,
                              void* d_out, int out_size, void* d_ws, size_t ws_size,
                              hipStream_t stream) {
    const float* x = (const float*)d_in[0];
    float* out = (float*)d_out;
    unsigned* ws = (unsigned*)d_ws;

    k_init<<<dim3(1), dim3(256), 0, stream>>>(ws);
    k_minmax<<<dim3(256), dim3(256), 0, stream>>>((const float4*)x, ws);
    k_main<<<dim3(H), dim3(256), 0, stream>>>(x, out, ws);
    k_final<<<dim3(1), dim3(64), 0, stream>>>(out, ws);
}

// Round 3
// 72.807 us; speedup vs baseline: 2.3971x; 1.0374x over previous
//
#include <hip/hip_runtime.h>

#define H 1024
#define W 1024
#define L 8
#define QH 1025
#define QW 1025
#define OUT0 192
#define QUANT_ELEMS (L * QH * QW)

#define CROWS 32              // rows per chunk
#define NCHUNK 32             // chunks (CROWS*NCHUNK == H)
#define BPC 72                // blocks per chunk: 64 co planes + 8 quant planes

// ws (u32/f32 slots): [0]=min_enc, [16]=max_enc, [32 + k*16]=sta[k]
#define WS_MIN 0
#define WS_MAX 16
#define WS_STA 32
#define WS_STRIDE 16
#define WS_SLOTS (WS_STA + 64 * WS_STRIDE)

__device__ __forceinline__ unsigned enc_ord(float f) {
    unsigned b = __float_as_uint(f);
    return (b & 0x80000000u) ? ~b : (b ^ 0x80000000u);
}
__device__ __forceinline__ float dec_ord(unsigned u) {
    unsigned b = (u & 0x80000000u) ? (u ^ 0x80000000u) : ~u;
    return __uint_as_float(b);
}
__device__ __forceinline__ float qlev(float mn, float step, float mx, int i) {
    return (i == L - 1) ? mx : mn + step * (float)i;
}

__global__ void k_init(unsigned* ws) {
    int t = threadIdx.x;
    for (int i = t; i < WS_SLOTS; i += 256)
        ws[i] = (i == WS_MIN) ? 0xFFFFFFFFu : 0u;  // float 0.0 == 0u bits
}

__global__ __launch_bounds__(256) void k_minmax(const float4* __restrict__ x4, unsigned* ws) {
    int t = threadIdx.x;
    int gid = blockIdx.x * 256 + t;
    float mn = 1e30f, mx = -1e30f;
    #pragma unroll
    for (int i = 0; i < 4; ++i) {
        float4 v = x4[gid + i * 65536];
        mn = fminf(mn, fminf(fminf(v.x, v.y), fminf(v.z, v.w)));
        mx = fmaxf(mx, fmaxf(fmaxf(v.x, v.y), fmaxf(v.z, v.w)));
    }
    #pragma unroll
    for (int m = 1; m < 64; m <<= 1) {
        mn = fminf(mn, __shfl_xor(mn, m, 64));
        mx = fmaxf(mx, __shfl_xor(mx, m, 64));
    }
    __shared__ float smn[4], smx[4];
    if ((t & 63) == 0) { smn[t >> 6] = mn; smx[t >> 6] = mx; }
    __syncthreads();
    if (t == 0) {
        mn = fminf(fminf(smn[0], smn[1]), fminf(smn[2], smn[3]));
        mx = fmaxf(fmaxf(smx[0], smx[1]), fmaxf(smx[2], smx[3]));
        atomicMin(&ws[WS_MIN], enc_ord(mn));
        atomicMax(&ws[WS_MAX], enc_ord(mx));
    }
}

// Plane-major: each block writes ONE contiguous region (fill-kernel-like DRAM
// stream). bid -> chunk c (shared x rows -> L2 reuse), plane k.
// k < 64: co plane (i=k>>3, j=k&7), rows [c*32, c*32+32), 128KB contiguous.
// k >= 64: quant plane i=k-64, same rows (+ pads).
__global__ __launch_bounds__(256) void k_main(const float* __restrict__ x,
                                              float* __restrict__ out,
                                              unsigned* __restrict__ ws) {
    const float mnv = dec_ord(ws[WS_MIN]);
    const float mxv = dec_ord(ws[WS_MAX]);
    const float step = (mxv - mnv) * (1.0f / 7.0f);

    float* __restrict__ quant = out + OUT0;
    float* __restrict__ co    = out + OUT0 + QUANT_ELEMS;

    const int bid = blockIdx.x;
    const int c = bid / BPC, k = bid - c * BPC;
    const int r0 = c * CROWS;
    const int t = threadIdx.x, w0 = t * 4;

    if (k < 64) {
        const int i = k >> 3, j = k & 7;
        const float qi = qlev(mnv, step, mxv, i);
        const float qj = qlev(mnv, step, mxv, j);
        float* cop = co + k * (H * W) + r0 * W + w0;
        float acc = 0.0f;

        for (int r = 0; r < CROWS; ++r) {
            const int h = r0 + r;
            float4 xl = *(const float4*)(x + h * W + w0);
            const bool hok = (h + 1 < H);
            float xr0 = 0.f, xr1 = 0.f, xr2 = 0.f, xr3 = 0.f;
            bool ok3 = false;
            if (hok) {
                float4 a = *(const float4*)(x + (h + 1) * W + w0);
                xr0 = a.y; xr1 = a.z; xr2 = a.w;
                ok3 = (w0 + 4 < W);                  // col w0+4==1024 -> pad
                if (ok3) xr3 = x[(h + 1) * W + w0 + 4];
            }
            float d;
            d = xl.x - qi; float l0 = __expf(-16.f * d * d);
            d = xl.y - qi; float l1 = __expf(-16.f * d * d);
            d = xl.z - qi; float l2 = __expf(-16.f * d * d);
            d = xl.w - qi; float l3 = __expf(-16.f * d * d);
            d = xr0 - qj; float p0 = hok ? __expf(-16.f * d * d) : 0.f;
            d = xr1 - qj; float p1 = hok ? __expf(-16.f * d * d) : 0.f;
            d = xr2 - qj; float p2 = hok ? __expf(-16.f * d * d) : 0.f;
            d = xr3 - qj; float p3 = (hok && ok3) ? __expf(-16.f * d * d) : 0.f;

            float4 v;
            v.x = l0 * p0; v.y = l1 * p1; v.z = l2 * p2; v.w = l3 * p3;
            *(float4*)cop = v;
            cop += W;
            acc += (v.x + v.y) + (v.z + v.w);
        }

        // block reduction: 6 shfl + LDS + ONE atomic per block (16 per sta line total)
        #pragma unroll
        for (int m = 1; m < 64; m <<= 1) acc += __shfl_xor(acc, m, 64);
        __shared__ float red[4];
        if ((t & 63) == 0) red[t >> 6] = acc;
        __syncthreads();
        if (t == 0)
            atomicAdd((float*)ws + WS_STA + k * WS_STRIDE,
                      (red[0] + red[1]) + (red[2] + red[3]));
    } else {
        const int i = k - 64;
        const float qi = qlev(mnv, step, mxv, i);
        for (int r = 0; r < CROWS; ++r) {
            const int h = r0 + r;
            float4 xl = *(const float4*)(x + h * W + w0);
            float d;
            d = xl.x - qi; float l0 = __expf(-16.f * d * d);
            d = xl.y - qi; float l1 = __expf(-16.f * d * d);
            d = xl.z - qi; float l2 = __expf(-16.f * d * d);
            d = xl.w - qi; float l3 = __expf(-16.f * d * d);
            float* row = quant + (i * QH + h) * QW + w0;
            row[0] = l0; row[1] = l1; row[2] = l2; row[3] = l3;
            if (t == 255) row[4] = 0.0f;             // right pad col (w0+4 == 1024)
        }
        if (c == NCHUNK - 1) {                        // bottom pad row h==1024
            for (int w = t; w < QW; w += 256)
                quant[(i * QH + H) * QW + w] = 0.0f;
        }
    }
}

__global__ void k_final(float* __restrict__ out, const unsigned* __restrict__ ws) {
    int t = threadIdx.x;  // 64 threads
    const float mnv = dec_ord(ws[WS_MIN]);
    const float mxv = dec_ord(ws[WS_MAX]);
    const float step = (mxv - mnv) * (1.0f / 7.0f);

    float s = ((const float*)ws)[WS_STA + t * WS_STRIDE];
    float tot = s;
    #pragma unroll
    for (int m = 1; m < 64; m <<= 1) tot += __shfl_xor(tot, m, 64);

    out[t]       = qlev(mnv, step, mxv, t & 7);   // q_h[i][j] = q_levels[j]
    out[64 + t]  = qlev(mnv, step, mxv, t >> 3);  // q_w[i][j] = q_levels[i]
    out[128 + t] = s / tot;                       // normalized sta
}

extern "C" void kernel_launch(void* const* d_in, const int* in_sizes, int n_in,
                              void* d_out, int out_size, void* d_ws, size_t ws_size,
                              hipStream_t stream) {
    const float* x = (const float*)d_in[0];
    float* out = (float*)d_out;
    unsigned* ws = (unsigned*)d_ws;

    k_init<<<dim3(1), dim3(256), 0, stream>>>(ws);
    k_minmax<<<dim3(256), dim3(256), 0, stream>>>((const float4*)x, ws);
    k_main<<<dim3(NCHUNK * BPC), dim3(256), 0, stream>>>(x, out, ws);
    k_final<<<dim3(1), dim3(64), 0, stream>>>(out, ws);
}